// Round 1
// baseline (274.755 us; speedup 1.0000x reference)
//
#include <hip/hip_runtime.h>

#define DD 64
#define NN 512
#define BB 4
#define NEG_SLOPE 0.01f

// ws layout (floats): cq[64], ck[64], cv[64], C (1)
__global__ void precompute_kernel(const float* __restrict__ W_w,
                                  const float* __restrict__ W_b,
                                  const float* __restrict__ a_w,
                                  const float* __restrict__ a_b,
                                  float* __restrict__ ws) {
    int d = threadIdx.x;  // 0..63
    float cq = 0.f, ck = 0.f, cv = 0.f;
    for (int e = 0; e < DD; ++e) {
        float w = W_w[e * DD + d];          // W_w[e,d], coalesced over d
        cq = fmaf(a_w[e], w, cq);
        ck = fmaf(a_w[DD + e], w, ck);
        cv = fmaf(a_w[2 * DD + e], w, cv);
    }
    ws[d] = cq;
    ws[DD + d] = ck;
    ws[2 * DD + d] = cv;
    // C = dot(W_b, a_q + a_k + a_v) + a_b[0]
    float p = W_b[d] * (a_w[d] + a_w[DD + d] + a_w[2 * DD + d]);
#pragma unroll
    for (int off = 32; off; off >>= 1) p += __shfl_down(p, off, 64);
    if (d == 0) ws[3 * DD] = p + a_b[0];
}

// one block per output row (b,i); 256 threads.
// thread t: d4 = t&15 (which float4 of the 64-d row), jl = t>>4 (which j in a 16-j group)
__global__ __launch_bounds__(256) void attn_row_kernel(
        const float* __restrict__ emb,
        const float* __restrict__ ws,
        float* __restrict__ out_alpha,
        float* __restrict__ out_value) {
    const int row = blockIdx.x;      // 0 .. BB*NN-1
    const int b = row >> 9;          // / NN
    const int t = threadIdx.x;
    const int d4 = t & 15;
    const int jl = t >> 4;

    __shared__ float s_lds[NN];
    __shared__ float red[8];

    const float4* emb4 = (const float4*)emb;
    const float4 ei = emb4[(size_t)row * 16 + d4];
    const float4 cq = ((const float4*)ws)[d4];
    const float4 ck = ((const float4*)(ws + DD))[d4];
    const float4 cv = ((const float4*)(ws + 2 * DD))[d4];
    const float Cc = ws[3 * DD];

    const float4* embB = emb4 + (size_t)b * NN * 16;      // emb[b,:,:]
    float4* val4 = (float4*)(out_value + (size_t)row * NN * DD);

    // partial of ei·cq: summing this over the 16 d4-lanes yields the full dot,
    // so it rides along in the same cross-lane reduction as the j-dependent terms.
    const float pq = ei.x * cq.x + ei.y * cq.y + ei.z * cq.z + ei.w * cq.w;

#pragma unroll 4
    for (int it = 0; it < NN / 16; ++it) {
        const int j = it * 16 + jl;
        const float4 ej = embB[j * 16 + d4];
        float4 p;
        p.x = ei.x * ej.x; p.y = ei.y * ej.y;
        p.z = ei.z * ej.z; p.w = ei.w * ej.w;
        val4[j * 16 + d4] = p;                             // value write, coalesced
        float v = p.x * cv.x + p.y * cv.y + p.z * cv.z + p.w * cv.w
                + ej.x * ck.x + ej.y * ck.y + ej.z * ck.z + ej.w * ck.w
                + pq;
        // reduce across the 16 lanes (bits 0..3 of lane id) sharing this j
        v += __shfl_xor(v, 1, 64);
        v += __shfl_xor(v, 2, 64);
        v += __shfl_xor(v, 4, 64);
        v += __shfl_xor(v, 8, 64);
        if (d4 == 0) {
            float s = v + Cc;
            s_lds[j] = (s >= 0.f) ? s : NEG_SLOPE * s;     // leaky relu
        }
    }
    __syncthreads();

    // block softmax over 512 entries (each thread owns 2)
    float s0 = s_lds[t], s1 = s_lds[t + 256];
    float m = fmaxf(s0, s1);
#pragma unroll
    for (int off = 32; off; off >>= 1) m = fmaxf(m, __shfl_xor(m, off, 64));
    const int wid = t >> 6, lane = t & 63;
    if (lane == 0) red[wid] = m;
    __syncthreads();
    m = fmaxf(fmaxf(red[0], red[1]), fmaxf(red[2], red[3]));

    float e0 = expf(s0 - m), e1 = expf(s1 - m);
    float ps = e0 + e1;
#pragma unroll
    for (int off = 32; off; off >>= 1) ps += __shfl_xor(ps, off, 64);
    if (lane == 0) red[4 + wid] = ps;
    __syncthreads();
    const float inv = 1.f / (red[4] + red[5] + red[6] + red[7]);

    float* arow = out_alpha + (size_t)row * NN;
    arow[t] = e0 * inv;
    arow[t + 256] = e1 * inv;
}

extern "C" void kernel_launch(void* const* d_in, const int* in_sizes, int n_in,
                              void* d_out, int out_size, void* d_ws, size_t ws_size,
                              hipStream_t stream) {
    const float* emb = (const float*)d_in[0];
    const float* W_w = (const float*)d_in[1];
    const float* W_b = (const float*)d_in[2];
    const float* a_w = (const float*)d_in[3];
    const float* a_b = (const float*)d_in[4];
    float* ws = (float*)d_ws;

    float* out = (float*)d_out;
    float* out_alpha = out;                                  // B*N*N floats
    float* out_value = out + (size_t)BB * NN * NN;           // B*N*N*D floats

    precompute_kernel<<<1, 64, 0, stream>>>(W_w, W_b, a_w, a_b, ws);
    attn_row_kernel<<<BB * NN, 256, 0, stream>>>(emb, ws, out_alpha, out_value);
}